// Round 1
// baseline (416.927 us; speedup 1.0000x reference)
//
#include <hip/hip_runtime.h>

// GCN layer: out = segment_sum(L_vals[:,None] * X[L_cols], L_rows) @ W^T + b
// Strategy: zero out -> atomic scatter (agg into d_out) -> in-place linear.
// N=100000 (div by 4), E=1600000 (div by 4), D=64. No workspace needed.

constexpr int D = 64;
constexpr int N_NODES = 100000;
constexpr int N_EDGES = 1600000;

// One wave (64 lanes) per edge; lane = feature index. 4 edges per 256-thr block.
__global__ __launch_bounds__(256) void gcn_scatter_kernel(
    const int* __restrict__ rows,
    const int* __restrict__ cols,
    const float* __restrict__ vals,
    const float* __restrict__ X,
    float* __restrict__ agg)
{
    const int e    = blockIdx.x * 4 + (threadIdx.x >> 6);
    const int lane = threadIdx.x & 63;
    const int r = rows[e];
    const int c = cols[e];
    const float v = vals[e];
    const float x = X[c * D + lane];
    atomicAdd(&agg[r * D + lane], v * x);
}

// In-place per-row linear: out_row = agg_row @ W^T + b.
// One wave per row; W staged in LDS padded [64][65] (2-way conflicts = free).
__global__ __launch_bounds__(256) void gcn_transform_kernel(
    const float* __restrict__ W,
    const float* __restrict__ bias,
    float* __restrict__ out)
{
    __shared__ float Wl[D][D + 1];
    __shared__ float rowbuf[4][D];

    const int tid = threadIdx.x;
    for (int i = tid; i < D * D; i += 256)
        Wl[i >> 6][i & 63] = W[i];

    const int wave = tid >> 6;
    const int lane = tid & 63;
    const int n = blockIdx.x * 4 + wave;   // N divisible by 4: no tail

    rowbuf[wave][lane] = out[n * D + lane];
    __syncthreads();

    float acc = bias[lane];
#pragma unroll
    for (int f = 0; f < D; ++f)
        acc += rowbuf[wave][f] * Wl[lane][f];

    out[n * D + lane] = acc;
}

extern "C" void kernel_launch(void* const* d_in, const int* in_sizes, int n_in,
                              void* d_out, int out_size, void* d_ws, size_t ws_size,
                              hipStream_t stream) {
    const int*   L_rows = (const int*)d_in[0];
    const int*   L_cols = (const int*)d_in[1];
    const float* L_vals = (const float*)d_in[2];
    const float* X      = (const float*)d_in[3];
    const float* W      = (const float*)d_in[4];
    const float* b      = (const float*)d_in[5];
    float* out = (float*)d_out;

    // 1) zero the aggregation buffer (d_out doubles as agg)
    hipMemsetAsync(out, 0, (size_t)out_size * sizeof(float), stream);

    // 2) scatter-add: agg[r,:] += v * X[c,:]
    gcn_scatter_kernel<<<N_EDGES / 4, 256, 0, stream>>>(L_rows, L_cols, L_vals, X, out);

    // 3) in-place linear: out = agg @ W^T + b
    gcn_transform_kernel<<<N_NODES / 4, 256, 0, stream>>>(W, b, out);
}